// Round 7
// baseline (228.673 us; speedup 1.0000x reference)
//
#include <hip/hip_runtime.h>
#include <hip/hip_bf16.h>

#define TT 8192
#define DD 64
#define BB 2
#define NROWS (BB * TT)  // 16384

typedef __attribute__((ext_vector_type(8))) short bf16x8;
typedef __attribute__((ext_vector_type(4))) short bf16x4;
typedef __attribute__((ext_vector_type(4))) float f32x4;

#define MFMA32 __builtin_amdgcn_mfma_f32_16x16x32_bf16

// PV matmul: legacy K=16 shape whose A-operand layout (row=lane&15,
// k=(lane>>4)*4+e) matches the S-MFMA D-layout directly -> no lane shuffle.
// (verified passing rounds 1-6)
static __device__ inline f32x4 pv_mfma16(bf16x4 a, bf16x4 b, f32x4 c) {
#if __has_builtin(__builtin_amdgcn_mfma_f32_16x16x16bf16_1k)
  return __builtin_amdgcn_mfma_f32_16x16x16bf16_1k(a, b, c, 0, 0, 0);
#else
  asm volatile("v_mfma_f32_16x16x16_bf16 %0, %1, %2, %0" : "+v"(c) : "v"(a), "v"(b));
  return c;
#endif
}

typedef __attribute__((address_space(1))) const unsigned int gu32;
typedef __attribute__((address_space(3))) unsigned int lu32;

// async global->LDS, 16B per lane; LDS dest = wave-uniform base + lane*16
__device__ inline void gld_lds16(const unsigned short* g, unsigned short* l) {
  __builtin_amdgcn_global_load_lds((gu32*)g, (lu32*)l, 16, 0, 0);
}

// ws layout: xb bf16[16384*64] (2MB) | xt bf16[2*64*8192] (2MB) | m fp32[16384] | mm fp32[16384]

__device__ inline unsigned short f2bf(float f) {
  unsigned int u = __float_as_uint(f);
  u += 0x7FFF + ((u >> 16) & 1);  // RNE
  return (unsigned short)(u >> 16);
}
__device__ inline float bf2f(unsigned short h) {
  return __uint_as_float(((unsigned int)h) << 16);
}
__device__ inline unsigned int pk2bf(float lo, float hi) {
  __hip_bfloat162 h = __float22bfloat162_rn(float2{lo, hi});
  union { __hip_bfloat162 h; unsigned int u; } cv;
  cv.h = h;
  return cv.u;
}

// ---------- ka: bf16 convert + m + xb + LDS-transposed xt ----------
__global__ __launch_bounds__(256) void ka_init(const float* __restrict__ x,
                                               unsigned short* __restrict__ xb,
                                               unsigned short* __restrict__ xt,
                                               float* __restrict__ m) {
  __shared__ __align__(16) unsigned short tile[64 * 72];
  int t = threadIdx.x;
  int r0 = blockIdx.x * 64;
  int rloc = t >> 2, part = t & 3;
  int r = r0 + rloc;
  const float4* px = (const float4*)(x + (size_t)r * DD + part * 16);
  unsigned short h[16];
  float msum = 0.f;
#pragma unroll
  for (int g = 0; g < 4; ++g) {
    float4 v = px[g];
    unsigned short h0 = f2bf(v.x), h1 = f2bf(v.y), h2 = f2bf(v.z), h3 = f2bf(v.w);
    h[g * 4 + 0] = h0; h[g * 4 + 1] = h1; h[g * 4 + 2] = h2; h[g * 4 + 3] = h3;
    float f0 = bf2f(h0), f1 = bf2f(h1), f2 = bf2f(h2), f3 = bf2f(h3);
    msum += f0 * f0 + f1 * f1 + f2 * f2 + f3 * f3;
  }
  uint4* xbr = (uint4*)(xb + (size_t)r * DD + part * 16);
#pragma unroll
  for (int g = 0; g < 2; ++g) {
    uint4 v;
    v.x = (unsigned int)h[g * 8 + 0] | ((unsigned int)h[g * 8 + 1] << 16);
    v.y = (unsigned int)h[g * 8 + 2] | ((unsigned int)h[g * 8 + 3] << 16);
    v.z = (unsigned int)h[g * 8 + 4] | ((unsigned int)h[g * 8 + 5] << 16);
    v.w = (unsigned int)h[g * 8 + 6] | ((unsigned int)h[g * 8 + 7] << 16);
    xbr[g] = v;
  }
#pragma unroll
  for (int k = 0; k < 16; ++k) tile[(part * 16 + k) * 72 + rloc] = h[k];
  msum += __shfl_xor(msum, 1, 64);
  msum += __shfl_xor(msum, 2, 64);
  if (part == 0) m[r] = msum;
  __syncthreads();
  int d = t >> 2, seg = t & 3;
  int b = r0 >> 13;
  int tcol = (r0 & (TT - 1)) + seg * 16;
  uint4 v0 = *(uint4*)(tile + d * 72 + seg * 16);
  uint4 v1 = *(uint4*)(tile + d * 72 + seg * 16 + 8);
  uint4* dst = (uint4*)(xt + ((size_t)b * DD + d) * TT + tcol);
  dst[0] = v0;
  dst[1] = v1;
}

// ---------- kb: mm_j = m_j + ln( sum_k exp(x_j.x_k - m_j) ) ----------
// 256 blocks x 16 waves (1 block/CU = 4 waves/SIMD, as R3). j-tile 64 per
// block (halves DMA bytes, doubles MFMA per staged byte); each wave sweeps a
// private 512-k range in 16 iters of 32-k with the R3-verified double-buffered
// LDS-DMA + counted vmcnt pipeline. No barriers in the loop.
__global__ __launch_bounds__(1024, 1) void kb_l(const unsigned short* __restrict__ xq,
                                                const float* __restrict__ m,
                                                float* __restrict__ mm) {
  __shared__ __align__(16) unsigned short kslab[16][2][2048];  // 128KB
  __shared__ float lpart[16][64];
  int w = threadIdx.x >> 6, lane = threadIdx.x & 63;
  int c = lane & 15, q = lane >> 4;
  int lid = blockIdx.x;  // 0..255
  int b = lid >> 7;
  int jt = lid & 127;
  int j0g = b * TT + jt * 64;
  bf16x8 a0[4], a1[4];
  f32x4 mv[4];
#pragma unroll
  for (int u = 0; u < 4; ++u) {
    const unsigned short* pr = xq + (size_t)(j0g + u * 16 + c) * DD + q * 8;
    a0[u] = *(const bf16x8*)pr;
    a1[u] = *(const bf16x8*)(pr + 32);
    mv[u] = *(const f32x4*)(m + j0g + u * 16 + 4 * q);
  }
  const unsigned short* xqb = xq + (size_t)(b * TT) * DD;
  int k0 = w * 512;
  int srow = lane >> 3;
  int sch = (lane & 7) ^ srow;  // 16B source-granule XOR swizzle (verified R3)
  unsigned short* sb = &kslab[w][0][0];
  auto stage = [&](int buf, int kbase) {
#pragma unroll
    for (int t = 0; t < 4; ++t)
      gld_lds16(xqb + (size_t)(kbase + t * 8 + srow) * DD + sch * 8,
                sb + buf * 2048 + t * 512);
  };
  stage(0, k0);
  float ls[4][4];
#pragma unroll
  for (int u = 0; u < 4; ++u)
#pragma unroll
    for (int e = 0; e < 4; ++e) ls[u][e] = 0.f;
  int o1 = (q ^ (c & 7)) * 8, o2 = ((q | 4) ^ (c & 7)) * 8;
  for (int it = 0; it < 16; ++it) {
    if (it < 15) {
      stage((it & 1) ^ 1, k0 + (it + 1) * 32);
      asm volatile("s_waitcnt vmcnt(4)" ::: "memory");
    } else {
      asm volatile("s_waitcnt vmcnt(0)" ::: "memory");
    }
    __builtin_amdgcn_sched_barrier(0);
    const unsigned short* kp = sb + (it & 1) * 2048;
    bf16x8 b00 = *(const bf16x8*)(kp + c * 64 + o1);
    bf16x8 b01 = *(const bf16x8*)(kp + c * 64 + o2);
    bf16x8 b10 = *(const bf16x8*)(kp + (c + 16) * 64 + o1);
    bf16x8 b11 = *(const bf16x8*)(kp + (c + 16) * 64 + o2);
    __builtin_amdgcn_s_setprio(1);
#pragma unroll
    for (int u = 0; u < 4; ++u) {
      f32x4 z = {0.f, 0.f, 0.f, 0.f};
      f32x4 acc0 = MFMA32(a0[u], b00, z, 0, 0, 0);
      acc0 = MFMA32(a1[u], b01, acc0, 0, 0, 0);
      f32x4 acc1 = MFMA32(a0[u], b10, z, 0, 0, 0);
      acc1 = MFMA32(a1[u], b11, acc1, 0, 0, 0);
#pragma unroll
      for (int e = 0; e < 4; ++e)
        ls[u][e] += __expf(acc0[e] - mv[u][e]) + __expf(acc1[e] - mv[u][e]);
    }
    __builtin_amdgcn_s_setprio(0);
  }
#pragma unroll
  for (int u = 0; u < 4; ++u)
#pragma unroll
    for (int e = 0; e < 4; ++e) {
      float v = ls[u][e];
      v += __shfl_xor(v, 1, 64);
      v += __shfl_xor(v, 2, 64);
      v += __shfl_xor(v, 4, 64);
      v += __shfl_xor(v, 8, 64);
      if (c == 0) lpart[w][u * 16 + 4 * q + e] = v;
    }
  __syncthreads();
  int t = threadIdx.x;
  if (t < 64) {
    float s = 0.f;
#pragma unroll
    for (int w2 = 0; w2 < 16; ++w2) s += lpart[w2][t];
    mm[j0g + t] = m[j0g + t] + __logf(s);
  }
}

// ---------- kc: out[b][d][i] = sum_j exp(x_j.x_i - mm_j) * x_j[d] ----------
// R3 skeleton with 32-j iterations (R0 body): 8 waves/block (32-i tile), each
// wave sweeps a private 1024-j range in 32 iters of 32-j. A staged via 2x4KB
// per-wave LDS-DMA double buffer; V + mm in REGISTERS via asm-pinned global
// loads, 2 static slots consumed only after the counted vmcnt(14) (no LDS V
// gather -> no bank conflicts). P feeds PV as K=16 MFMAs, zero shuffle.
__global__ __launch_bounds__(512) void kc_out(const unsigned short* __restrict__ xq,
                                              const unsigned short* __restrict__ xt,
                                              const float* __restrict__ mm,
                                              float* __restrict__ out) {
  __shared__ __align__(16) unsigned short smem[36864];  // A 8x8KB=64KB | 72KB epilogue overlay
  int w = threadIdx.x >> 6, lane = threadIdx.x & 63;
  int c = lane & 15, q = lane >> 4;
  int lid = blockIdx.x;
  int b = (lid >> 2) & 1;
  int tile = (lid & 3) | ((lid >> 3) << 2);
  int i0 = tile * 32;
  bf16x8 bq0[2], bq1[2];
#pragma unroll
  for (int u = 0; u < 2; ++u) {
    const unsigned short* pr = xq + (size_t)(b * TT + i0 + u * 16 + c) * DD + q * 8;
    bq0[u] = *(const bf16x8*)pr;
    bq1[u] = *(const bf16x8*)(pr + 32);
  }
  f32x4 o[2][4];
#pragma unroll
  for (int u = 0; u < 2; ++u)
#pragma unroll
    for (int nt = 0; nt < 4; ++nt) o[u][nt] = (f32x4){0.f, 0.f, 0.f, 0.f};

  const unsigned short* xqb = xq + (size_t)(b * TT) * DD;
  const unsigned short* xtb = xt + (size_t)b * DD * TT;
  const float* mmb = mm + b * TT;
  int jq0 = w * 1024;
  unsigned short* asb = smem + w * 4096;  // 2 bufs x 2048 shorts (32 rows x 128B)
  int srow = lane >> 3;
  int sch = (lane & 7) ^ srow;            // 16B source-granule XOR swizzle (verified R3)
  const unsigned short* pv0 = xtb + (size_t)c * TT + 4 * q;  // V: d-row c(+nt*16), col 4q
  int o1 = (q ^ (c & 7)) * 8, o2 = ((q | 4) ^ (c & 7)) * 8;

  // 2-slot register prefetch state: V lo/hi (8B each) + mm (2x16B)
  unsigned long long vA0[2], vA1[2], vA2[2], vA3[2];
  unsigned long long vB0[2], vB1[2], vB2[2], vB3[2];
  f32x4 pm0[2], pm1[2];

#define KC_ISSUE(S, jn) do { \
    __builtin_amdgcn_sched_barrier(0); \
    gld_lds16(xqb + (size_t)((jn) + 0 + srow) * DD + sch * 8, asb + (S) * 2048 + 0); \
    gld_lds16(xqb + (size_t)((jn) + 8 + srow) * DD + sch * 8, asb + (S) * 2048 + 512); \
    gld_lds16(xqb + (size_t)((jn) + 16 + srow) * DD + sch * 8, asb + (S) * 2048 + 1024); \
    gld_lds16(xqb + (size_t)((jn) + 24 + srow) * DD + sch * 8, asb + (S) * 2048 + 1536); \
    __builtin_amdgcn_sched_barrier(0); \
    { const unsigned short* pj = pv0 + (jn); \
      asm volatile("global_load_dwordx2 %0, %1, off" : "=v"(vA0[S]) : "v"(pj)); \
      asm volatile("global_load_dwordx2 %0, %1, off" : "=v"(vA1[S]) : "v"(pj + 16 * TT)); \
      asm volatile("global_load_dwordx2 %0, %1, off" : "=v"(vA2[S]) : "v"(pj + 32 * TT)); \
      asm volatile("global_load_dwordx2 %0, %1, off" : "=v"(vA3[S]) : "v"(pj + 48 * TT)); \
      asm volatile("global_load_dwordx2 %0, %1, off" : "=v"(vB0[S]) : "v"(pj + 16)); \
      asm volatile("global_load_dwordx2 %0, %1, off" : "=v"(vB1[S]) : "v"(pj + 16 * TT + 16)); \
      asm volatile("global_load_dwordx2 %0, %1, off" : "=v"(vB2[S]) : "v"(pj + 32 * TT + 16)); \
      asm volatile("global_load_dwordx2 %0, %1, off" : "=v"(vB3[S]) : "v"(pj + 48 * TT + 16)); \
      asm volatile("global_load_dwordx4 %0, %1, off" : "=v"(pm0[S]) : "v"(mmb + (jn) + 4 * q)); \
      asm volatile("global_load_dwordx4 %0, %1, off" : "=v"(pm1[S]) : "v"(mmb + (jn) + 16 + 4 * q)); } \
    __builtin_amdgcn_sched_barrier(0); \
  } while (0)
#define KC_WAIT(N) do { \
    asm volatile("s_waitcnt vmcnt(" #N ")" ::: "memory"); \
    __builtin_amdgcn_sched_barrier(0); \
  } while (0)
#define KC_BODY(S) do { \
    const unsigned short* ap = asb + (S) * 2048; \
    bf16x8 a00 = *(const bf16x8*)(ap + c * 64 + o1); \
    bf16x8 a01 = *(const bf16x8*)(ap + c * 64 + o2); \
    bf16x8 a10 = *(const bf16x8*)(ap + (c + 16) * 64 + o1); \
    bf16x8 a11 = *(const bf16x8*)(ap + (c + 16) * 64 + o2); \
    union { unsigned long long u; bf16x4 v; } l0_, l1_, l2_, l3_, h0_, h1_, h2_, h3_; \
    l0_.u = vA0[S]; l1_.u = vA1[S]; l2_.u = vA2[S]; l3_.u = vA3[S]; \
    h0_.u = vB0[S]; h1_.u = vB1[S]; h2_.u = vB2[S]; h3_.u = vB3[S]; \
    f32x4 cmm0 = pm0[S], cmm1 = pm1[S]; \
    __builtin_amdgcn_s_setprio(1); \
    _Pragma("unroll") for (int u = 0; u < 2; ++u) { \
      f32x4 z = {0.f, 0.f, 0.f, 0.f}; \
      f32x4 s0 = MFMA32(a00, bq0[u], z, 0, 0, 0); \
      s0 = MFMA32(a01, bq1[u], s0, 0, 0, 0); \
      f32x4 s1 = MFMA32(a10, bq0[u], z, 0, 0, 0); \
      s1 = MFMA32(a11, bq1[u], s1, 0, 0, 0); \
      float w00 = __expf(s0[0] - cmm0[0]); \
      float w01 = __expf(s0[1] - cmm0[1]); \
      float w02 = __expf(s0[2] - cmm0[2]); \
      float w03 = __expf(s0[3] - cmm0[3]); \
      float w10 = __expf(s1[0] - cmm1[0]); \
      float w11 = __expf(s1[1] - cmm1[1]); \
      float w12 = __expf(s1[2] - cmm1[2]); \
      float w13 = __expf(s1[3] - cmm1[3]); \
      union { unsigned int uu[2]; bf16x4 v; } pA, pB; \
      pA.uu[0] = pk2bf(w00, w01); \
      pA.uu[1] = pk2bf(w02, w03); \
      pB.uu[0] = pk2bf(w10, w11); \
      pB.uu[1] = pk2bf(w12, w13); \
      o[u][0] = pv_mfma16(pA.v, l0_.v, o[u][0]); \
      o[u][1] = pv_mfma16(pA.v, l1_.v, o[u][1]); \
      o[u][2] = pv_mfma16(pA.v, l2_.v, o[u][2]); \
      o[u][3] = pv_mfma16(pA.v, l3_.v, o[u][3]); \
      o[u][0] = pv_mfma16(pB.v, h0_.v, o[u][0]); \
      o[u][1] = pv_mfma16(pB.v, h1_.v, o[u][1]); \
      o[u][2] = pv_mfma16(pB.v, h2_.v, o[u][2]); \
      o[u][3] = pv_mfma16(pB.v, h3_.v, o[u][3]); \
    } \
    __builtin_amdgcn_s_setprio(0); \
  } while (0)

  KC_ISSUE(0, jq0);
  for (int g = 0; g < 15; ++g) {
    int jb = jq0 + g * 64;
    KC_ISSUE(1, jb + 32); KC_WAIT(14); KC_BODY(0);
    KC_ISSUE(0, jb + 64); KC_WAIT(14); KC_BODY(1);
  }
  KC_ISSUE(1, jq0 + 992); KC_WAIT(14); KC_BODY(0);
  KC_WAIT(0); KC_BODY(1);

  // cross-wave O reduce: Olds[w][d 64][pitch 36 fp32], overlays A-slabs
  __syncthreads();
  float* ow = (float*)smem + w * 2304;
#pragma unroll
  for (int u = 0; u < 2; ++u)
#pragma unroll
    for (int nt = 0; nt < 4; ++nt)
      *(f32x4*)(ow + (nt * 16 + c) * 36 + u * 16 + 4 * q) = o[u][nt];
  __syncthreads();
  int t = threadIdx.x, d = t & 63, g = t >> 6;  // g = 0..7 -> 4 i's each
  const float* sbase = (const float*)smem;
  f32x4 sA = {0.f, 0.f, 0.f, 0.f};
#pragma unroll
  for (int w2 = 0; w2 < 8; ++w2)
    sA += *(const f32x4*)(sbase + w2 * 2304 + d * 36 + g * 4);
  *(f32x4*)(out + ((size_t)(b * DD + d)) * TT + i0 + g * 4) = sA;
}

extern "C" void kernel_launch(void* const* d_in, const int* in_sizes, int n_in,
                              void* d_out, int out_size, void* d_ws, size_t ws_size,
                              hipStream_t stream) {
  const float* x = (const float*)d_in[0];
  float* out = (float*)d_out;
  unsigned short* xb = (unsigned short*)d_ws;
  unsigned short* xt = xb + (size_t)NROWS * DD;
  float* m = (float*)(xt + (size_t)NROWS * DD);
  float* mmv = m + NROWS;

  ka_init<<<NROWS / 64, 256, 0, stream>>>(x, xb, xt, m);
  kb_l<<<256, 1024, 0, stream>>>(xb, m, mmv);
  kc_out<<<512, 512, 0, stream>>>(xb, xt, mmv, out);
}

// Round 9
// 182.709 us; speedup vs baseline: 1.2516x; 1.2516x over previous
//
#include <hip/hip_runtime.h>
#include <hip/hip_bf16.h>

#define TT 8192
#define DD 64
#define BB 2
#define NROWS (BB * TT)  // 16384

typedef __attribute__((ext_vector_type(8))) short bf16x8;
typedef __attribute__((ext_vector_type(4))) short bf16x4;
typedef __attribute__((ext_vector_type(4))) float f32x4;

#define MFMA32 __builtin_amdgcn_mfma_f32_16x16x32_bf16

// PV matmul: legacy K=16 shape whose A-operand layout (row=lane&15,
// k=(lane>>4)*4+e) matches the S-MFMA D-layout directly -> no lane shuffle.
// (verified passing rounds 1-7)
static __device__ inline f32x4 pv_mfma16(bf16x4 a, bf16x4 b, f32x4 c) {
#if __has_builtin(__builtin_amdgcn_mfma_f32_16x16x16bf16_1k)
  return __builtin_amdgcn_mfma_f32_16x16x16bf16_1k(a, b, c, 0, 0, 0);
#else
  asm volatile("v_mfma_f32_16x16x16_bf16 %0, %1, %2, %0" : "+v"(c) : "v"(a), "v"(b));
  return c;
#endif
}

typedef __attribute__((address_space(1))) const unsigned int gu32;
typedef __attribute__((address_space(3))) unsigned int lu32;

// async global->LDS, 16B per lane; LDS dest = wave-uniform base + lane*16
__device__ inline void gld_lds16(const unsigned short* g, unsigned short* l) {
  __builtin_amdgcn_global_load_lds((gu32*)g, (lu32*)l, 16, 0, 0);
}

// ws layout: xb bf16[16384*64] (2MB) | xt bf16[2*64*8192] (2MB) | m fp32[16384] | mm fp32[16384]

__device__ inline unsigned short f2bf(float f) {
  unsigned int u = __float_as_uint(f);
  u += 0x7FFF + ((u >> 16) & 1);  // RNE
  return (unsigned short)(u >> 16);
}
__device__ inline float bf2f(unsigned short h) {
  return __uint_as_float(((unsigned int)h) << 16);
}
__device__ inline unsigned int pk2bf(float lo, float hi) {
  __hip_bfloat162 h = __float22bfloat162_rn(float2{lo, hi});
  union { __hip_bfloat162 h; unsigned int u; } cv;
  cv.h = h;
  return cv.u;
}

// ---------- ka: bf16 convert + m + xb + LDS-transposed xt (R3 verbatim) ----------
__global__ __launch_bounds__(256) void ka_init(const float* __restrict__ x,
                                               unsigned short* __restrict__ xb,
                                               unsigned short* __restrict__ xt,
                                               float* __restrict__ m) {
  __shared__ __align__(16) unsigned short tile[64 * 72];
  int t = threadIdx.x;
  int r0 = blockIdx.x * 64;
  int rloc = t >> 2, part = t & 3;
  int r = r0 + rloc;
  const float4* px = (const float4*)(x + (size_t)r * DD + part * 16);
  unsigned short h[16];
  float msum = 0.f;
#pragma unroll
  for (int g = 0; g < 4; ++g) {
    float4 v = px[g];
    unsigned short h0 = f2bf(v.x), h1 = f2bf(v.y), h2 = f2bf(v.z), h3 = f2bf(v.w);
    h[g * 4 + 0] = h0; h[g * 4 + 1] = h1; h[g * 4 + 2] = h2; h[g * 4 + 3] = h3;
    float f0 = bf2f(h0), f1 = bf2f(h1), f2 = bf2f(h2), f3 = bf2f(h3);
    msum += f0 * f0 + f1 * f1 + f2 * f2 + f3 * f3;
  }
  uint4* xbr = (uint4*)(xb + (size_t)r * DD + part * 16);
#pragma unroll
  for (int g = 0; g < 2; ++g) {
    uint4 v;
    v.x = (unsigned int)h[g * 8 + 0] | ((unsigned int)h[g * 8 + 1] << 16);
    v.y = (unsigned int)h[g * 8 + 2] | ((unsigned int)h[g * 8 + 3] << 16);
    v.z = (unsigned int)h[g * 8 + 4] | ((unsigned int)h[g * 8 + 5] << 16);
    v.w = (unsigned int)h[g * 8 + 6] | ((unsigned int)h[g * 8 + 7] << 16);
    xbr[g] = v;
  }
#pragma unroll
  for (int k = 0; k < 16; ++k) tile[(part * 16 + k) * 72 + rloc] = h[k];
  msum += __shfl_xor(msum, 1, 64);
  msum += __shfl_xor(msum, 2, 64);
  if (part == 0) m[r] = msum;
  __syncthreads();
  int d = t >> 2, seg = t & 3;
  int b = r0 >> 13;
  int tcol = (r0 & (TT - 1)) + seg * 16;
  uint4 v0 = *(uint4*)(tile + d * 72 + seg * 16);
  uint4 v1 = *(uint4*)(tile + d * 72 + seg * 16 + 8);
  uint4* dst = (uint4*)(xt + ((size_t)b * DD + d) * TT + tcol);
  dst[0] = v0;
  dst[1] = v1;
}

// ---------- kb: mm_j = m_j + ln( sum_k exp(x_j.x_k - m_j) ) (R3 verbatim) ----------
__global__ __launch_bounds__(512, 2) void kb_l(const unsigned short* __restrict__ xq,
                                               const float* __restrict__ m,
                                               float* __restrict__ mm) {
  __shared__ __align__(16) unsigned short kslab[8][2][2048];
  __shared__ float lpart[8][32];
  int w = threadIdx.x >> 6, lane = threadIdx.x & 63;
  int c = lane & 15, q = lane >> 4;
  int lid = blockIdx.x;
  int b = (lid >> 2) & 1;
  int tile = (lid & 3) | ((lid >> 3) << 2);  // 0..255
  int j0g = b * TT + tile * 32;
  bf16x8 a0[2], a1[2];
  f32x4 mv[2];
#pragma unroll
  for (int u = 0; u < 2; ++u) {
    const unsigned short* pr = xq + (size_t)(j0g + u * 16 + c) * DD + q * 8;
    a0[u] = *(const bf16x8*)pr;
    a1[u] = *(const bf16x8*)(pr + 32);
    mv[u] = *(const f32x4*)(m + j0g + u * 16 + 4 * q);
  }
  const unsigned short* xqb = xq + (size_t)(b * TT) * DD;
  int k0 = w * 1024;
  int srow = lane >> 3;
  int sch = (lane & 7) ^ srow;
  unsigned short* sb = &kslab[w][0][0];
  auto stage = [&](int buf, int kbase) {
#pragma unroll
    for (int t = 0; t < 4; ++t)
      gld_lds16(xqb + (size_t)(kbase + t * 8 + srow) * DD + sch * 8,
                sb + buf * 2048 + t * 512);
  };
  stage(0, k0);
  float ls[2][4] = {{0.f, 0.f, 0.f, 0.f}, {0.f, 0.f, 0.f, 0.f}};
  int o1 = (q ^ (c & 7)) * 8, o2 = ((q | 4) ^ (c & 7)) * 8;
  for (int it = 0; it < 32; ++it) {
    if (it < 31) {
      stage((it & 1) ^ 1, k0 + (it + 1) * 32);
      asm volatile("s_waitcnt vmcnt(4)" ::: "memory");
    } else {
      asm volatile("s_waitcnt vmcnt(0)" ::: "memory");
    }
    __builtin_amdgcn_sched_barrier(0);
    const unsigned short* kp = sb + (it & 1) * 2048;
    bf16x8 b00 = *(const bf16x8*)(kp + c * 64 + o1);
    bf16x8 b01 = *(const bf16x8*)(kp + c * 64 + o2);
    bf16x8 b10 = *(const bf16x8*)(kp + (c + 16) * 64 + o1);
    bf16x8 b11 = *(const bf16x8*)(kp + (c + 16) * 64 + o2);
    __builtin_amdgcn_s_setprio(1);
#pragma unroll
    for (int u = 0; u < 2; ++u) {
      f32x4 z = {0.f, 0.f, 0.f, 0.f};
      f32x4 acc0 = MFMA32(a0[u], b00, z, 0, 0, 0);
      acc0 = MFMA32(a1[u], b01, acc0, 0, 0, 0);
      f32x4 acc1 = MFMA32(a0[u], b10, z, 0, 0, 0);
      acc1 = MFMA32(a1[u], b11, acc1, 0, 0, 0);
#pragma unroll
      for (int e = 0; e < 4; ++e)
        ls[u][e] += __expf(acc0[e] - mv[u][e]) + __expf(acc1[e] - mv[u][e]);
    }
    __builtin_amdgcn_s_setprio(0);
  }
#pragma unroll
  for (int u = 0; u < 2; ++u)
#pragma unroll
    for (int e = 0; e < 4; ++e) {
      float v = ls[u][e];
      v += __shfl_xor(v, 1, 64);
      v += __shfl_xor(v, 2, 64);
      v += __shfl_xor(v, 4, 64);
      v += __shfl_xor(v, 8, 64);
      if (c == 0) lpart[w][u * 16 + 4 * q + e] = v;
    }
  __syncthreads();
  int t = threadIdx.x;
  if (t < 32) {
    float s = 0.f;
#pragma unroll
    for (int w2 = 0; w2 < 8; ++w2) s += lpart[w2][t];
    mm[j0g + t] = m[j0g + t] + __logf(s);
  }
}

// ---------- kc: out[b][d][i] = sum_j exp(x_j.x_i - mm_j) * x_j[d] ----------
// R3 structure; V path reg-staged (T14) into a 48B-pitch padded LDS buffer
// (2-way banks = free) instead of DMA into 32B-pitch rows (4-8-way, 12.6M
// conflict cycles in R3). A-DMA, fragment math, mm mapping, epilogue verbatim
// from verified rounds. Per chunk: issue [2 V asm][1 mm asm][2 A-DMA] = 5;
// vmcnt(5) before body, vmcnt(3) before the V ds_write. 2-slot unrolled loop
// (named slot vars, no runtime indexing).
__global__ __launch_bounds__(512, 2) void kc_out(const unsigned short* __restrict__ xq,
                                                 const unsigned short* __restrict__ xt,
                                                 const float* __restrict__ mm,
                                                 float* __restrict__ out) {
  // A slabs 8w x 2buf x 1024 shorts = 32KB | V slabs 8w x 2buf x 1536 shorts
  // (64 rows x 24-short pitch) = 48KB | epilogue overlay 72KB -> 80KB total
  __shared__ __align__(16) unsigned short smem[40960];
  int w = threadIdx.x >> 6, lane = threadIdx.x & 63;
  int c = lane & 15, q = lane >> 4;
  int lid = blockIdx.x;
  int b = (lid >> 2) & 1;
  int tile = (lid & 3) | ((lid >> 3) << 2);
  int i0 = tile * 32;
  bf16x8 bq0[2], bq1[2];
#pragma unroll
  for (int u = 0; u < 2; ++u) {
    const unsigned short* pr = xq + (size_t)(b * TT + i0 + u * 16 + c) * DD + q * 8;
    bq0[u] = *(const bf16x8*)pr;
    bq1[u] = *(const bf16x8*)(pr + 32);
  }
  f32x4 o[2][4];
#pragma unroll
  for (int u = 0; u < 2; ++u)
#pragma unroll
    for (int nt = 0; nt < 4; ++nt) o[u][nt] = (f32x4){0.f, 0.f, 0.f, 0.f};

  const unsigned short* xqb = xq + (size_t)(b * TT) * DD;
  const unsigned short* xtb = xt + (size_t)b * DD * TT;
  const float* mmb = mm + b * TT;
  int jq0 = w * 1024;
  unsigned short* asb = smem + w * 2048;           // 2 bufs x 1024 shorts (16 rows x 128B)
  unsigned short* vsb = smem + 16384 + w * 3072;   // 2 bufs x 1536 shorts (64 rows x 48B)
  int srow = lane >> 3;
  int sch = (lane & 7) ^ srow;        // A source-granule swizzle (verified R3)
  const unsigned short* pvrow = xtb + (size_t)lane * TT;  // this lane's V d-row
  int o1 = (q ^ (c & 7)) * 8, o2 = ((q | 4) ^ (c & 7)) * 8;

  // 2-slot register state: V 2x16B + mm 16B per slot (named, no runtime idx)
  f32x4 vA0, vB0, pmS0, vA1, vB1, pmS1;

#define KC_ISSUE(VA, VB, PM, ABUF, jn) do { \
    __builtin_amdgcn_sched_barrier(0); \
    { const unsigned short* pj = pvrow + (jn); \
      asm volatile("global_load_dwordx4 %0, %1, off" : "=v"(VA) : "v"(pj)); \
      asm volatile("global_load_dwordx4 %0, %1, off" : "=v"(VB) : "v"(pj + 8)); \
      asm volatile("global_load_dwordx4 %0, %1, off" : "=v"(PM) : "v"(mmb + (jn) + 4 * q)); } \
    __builtin_amdgcn_sched_barrier(0); \
    gld_lds16(xqb + (size_t)((jn) + srow) * DD + sch * 8, asb + (ABUF) * 1024); \
    gld_lds16(xqb + (size_t)((jn) + 8 + srow) * DD + sch * 8, asb + (ABUF) * 1024 + 512); \
    __builtin_amdgcn_sched_barrier(0); \
  } while (0)
#define KC_WAIT(N) do { \
    asm volatile("s_waitcnt vmcnt(" #N ")" ::: "memory"); \
    __builtin_amdgcn_sched_barrier(0); \
  } while (0)
#define KC_VWRITE(VA, VB, VBUF) do { \
    unsigned short* vw = vsb + (VBUF) * 1536 + lane * 24; \
    *(f32x4*)vw = VA; \
    *(f32x4*)(vw + 8) = VB; \
  } while (0)
#define KC_BODY(ABUF, VBUF, PM) do { \
    const unsigned short* ap = asb + (ABUF) * 1024; \
    const unsigned short* vp = vsb + (VBUF) * 1536; \
    bf16x8 a00 = *(const bf16x8*)(ap + c * 64 + o1); \
    bf16x8 a01 = *(const bf16x8*)(ap + c * 64 + o2); \
    bf16x4 bv[4]; \
    _Pragma("unroll") for (int nt = 0; nt < 4; ++nt) \
      bv[nt] = *(const bf16x4*)(vp + (nt * 16 + c) * 24 + 4 * q); \
    f32x4 cmm = PM; \
    __builtin_amdgcn_s_setprio(1); \
    _Pragma("unroll") for (int u = 0; u < 2; ++u) { \
      f32x4 z = {0.f, 0.f, 0.f, 0.f}; \
      f32x4 s0 = MFMA32(a00, bq0[u], z, 0, 0, 0); \
      s0 = MFMA32(a01, bq1[u], s0, 0, 0, 0); \
      float w00 = __expf(s0[0] - cmm[0]); \
      float w01 = __expf(s0[1] - cmm[1]); \
      float w02 = __expf(s0[2] - cmm[2]); \
      float w03 = __expf(s0[3] - cmm[3]); \
      union { unsigned int uu[2]; bf16x4 v; } plo; \
      plo.uu[0] = pk2bf(w00, w01); \
      plo.uu[1] = pk2bf(w02, w03); \
      o[u][0] = pv_mfma16(plo.v, bv[0], o[u][0]); \
      o[u][1] = pv_mfma16(plo.v, bv[1], o[u][1]); \
      o[u][2] = pv_mfma16(plo.v, bv[2], o[u][2]); \
      o[u][3] = pv_mfma16(plo.v, bv[3], o[u][3]); \
    } \
    __builtin_amdgcn_s_setprio(0); \
  } while (0)

  // prologue: stage chunk 0 into slot0/buf0, write its V
  KC_ISSUE(vA0, vB0, pmS0, 0, jq0);
  KC_WAIT(3);
  KC_VWRITE(vA0, vB0, 0);
  // main: 31 x 2 chunks (0..61 consumed, 62 staged at loop exit)
  for (int g = 0; g < 31; ++g) {
    int jb = jq0 + g * 32;
    KC_ISSUE(vA1, vB1, pmS1, 1, jb + 16);
    KC_WAIT(5);
    KC_BODY(0, 0, pmS0);
    KC_WAIT(3);
    KC_VWRITE(vA1, vB1, 1);
    KC_ISSUE(vA0, vB0, pmS0, 0, jb + 32);
    KC_WAIT(5);
    KC_BODY(1, 1, pmS1);
    KC_WAIT(3);
    KC_VWRITE(vA0, vB0, 0);
  }
  // epilogue: chunks 62 (slot0/buf0, already staged+written) and 63
  KC_ISSUE(vA1, vB1, pmS1, 1, jq0 + 1008);
  KC_WAIT(5);
  KC_BODY(0, 0, pmS0);
  KC_WAIT(3);
  KC_VWRITE(vA1, vB1, 1);
  KC_WAIT(0);
  KC_BODY(1, 1, pmS1);

  // cross-wave O reduce: Olds[w][d 64][pitch 36 fp32], overlays slabs (R3 verbatim)
  __syncthreads();
  float* ow = (float*)smem + w * 2304;
#pragma unroll
  for (int u = 0; u < 2; ++u)
#pragma unroll
    for (int nt = 0; nt < 4; ++nt)
      *(f32x4*)(ow + (nt * 16 + c) * 36 + u * 16 + 4 * q) = o[u][nt];
  __syncthreads();
  int t = threadIdx.x, d = t & 63, g = t >> 6;  // g = 0..7 -> 4 i's each
  const float* sbase = (const float*)smem;
  f32x4 sA = {0.f, 0.f, 0.f, 0.f};
#pragma unroll
  for (int w2 = 0; w2 < 8; ++w2)
    sA += *(const f32x4*)(sbase + w2 * 2304 + d * 36 + g * 4);
  *(f32x4*)(out + ((size_t)(b * DD + d)) * TT + i0 + g * 4) = sA;
}

extern "C" void kernel_launch(void* const* d_in, const int* in_sizes, int n_in,
                              void* d_out, int out_size, void* d_ws, size_t ws_size,
                              hipStream_t stream) {
  const float* x = (const float*)d_in[0];
  float* out = (float*)d_out;
  unsigned short* xb = (unsigned short*)d_ws;
  unsigned short* xt = xb + (size_t)NROWS * DD;
  float* m = (float*)(xt + (size_t)NROWS * DD);
  float* mmv = m + NROWS;

  ka_init<<<NROWS / 64, 256, 0, stream>>>(x, xb, xt, m);
  kb_l<<<512, 512, 0, stream>>>(xb, m, mmv);
  kc_out<<<512, 512, 0, stream>>>(xb, xt, mmv, out);
}

// Round 10
// 148.357 us; speedup vs baseline: 1.5414x; 1.2316x over previous
//
#include <hip/hip_runtime.h>
#include <hip/hip_bf16.h>

#define TT 8192
#define DD 64
#define BB 2
#define NROWS (BB * TT)  // 16384

typedef __attribute__((ext_vector_type(8))) short bf16x8;
typedef __attribute__((ext_vector_type(4))) short bf16x4;
typedef __attribute__((ext_vector_type(4))) float f32x4;

#define MFMA32 __builtin_amdgcn_mfma_f32_16x16x32_bf16

// PV matmul: legacy K=16 shape whose A-operand layout (row=lane&15,
// k=(lane>>4)*4+e) matches the S-MFMA D-layout directly -> no lane shuffle.
// (verified passing rounds 1-9)
static __device__ inline f32x4 pv_mfma16(bf16x4 a, bf16x4 b, f32x4 c) {
#if __has_builtin(__builtin_amdgcn_mfma_f32_16x16x16bf16_1k)
  return __builtin_amdgcn_mfma_f32_16x16x16bf16_1k(a, b, c, 0, 0, 0);
#else
  asm volatile("v_mfma_f32_16x16x16_bf16 %0, %1, %2, %0" : "+v"(c) : "v"(a), "v"(b));
  return c;
#endif
}

typedef __attribute__((address_space(1))) const unsigned int gu32;
typedef __attribute__((address_space(3))) unsigned int lu32;

// async global->LDS, 16B per lane; LDS dest = wave-uniform base + lane*16
__device__ inline void gld_lds16(const unsigned short* g, unsigned short* l) {
  __builtin_amdgcn_global_load_lds((gu32*)g, (lu32*)l, 16, 0, 0);
}

// ws layout: xb bf16[16384*64] (2MB) | xt bf16[2*64*8192] (2MB) | m fp32[16384] | mm fp32[16384]

__device__ inline unsigned short f2bf(float f) {
  unsigned int u = __float_as_uint(f);
  u += 0x7FFF + ((u >> 16) & 1);  // RNE
  return (unsigned short)(u >> 16);
}
__device__ inline float bf2f(unsigned short h) {
  return __uint_as_float(((unsigned int)h) << 16);
}
__device__ inline unsigned int pk2bf(float lo, float hi) {
  __hip_bfloat162 h = __float22bfloat162_rn(float2{lo, hi});
  union { __hip_bfloat162 h; unsigned int u; } cv;
  cv.h = h;
  return cv.u;
}

// ---------- ka: bf16 convert + m + xb + LDS-transposed xt (R3 verbatim) ----------
__global__ __launch_bounds__(256) void ka_init(const float* __restrict__ x,
                                               unsigned short* __restrict__ xb,
                                               unsigned short* __restrict__ xt,
                                               float* __restrict__ m) {
  __shared__ __align__(16) unsigned short tile[64 * 72];
  int t = threadIdx.x;
  int r0 = blockIdx.x * 64;
  int rloc = t >> 2, part = t & 3;
  int r = r0 + rloc;
  const float4* px = (const float4*)(x + (size_t)r * DD + part * 16);
  unsigned short h[16];
  float msum = 0.f;
#pragma unroll
  for (int g = 0; g < 4; ++g) {
    float4 v = px[g];
    unsigned short h0 = f2bf(v.x), h1 = f2bf(v.y), h2 = f2bf(v.z), h3 = f2bf(v.w);
    h[g * 4 + 0] = h0; h[g * 4 + 1] = h1; h[g * 4 + 2] = h2; h[g * 4 + 3] = h3;
    float f0 = bf2f(h0), f1 = bf2f(h1), f2 = bf2f(h2), f3 = bf2f(h3);
    msum += f0 * f0 + f1 * f1 + f2 * f2 + f3 * f3;
  }
  uint4* xbr = (uint4*)(xb + (size_t)r * DD + part * 16);
#pragma unroll
  for (int g = 0; g < 2; ++g) {
    uint4 v;
    v.x = (unsigned int)h[g * 8 + 0] | ((unsigned int)h[g * 8 + 1] << 16);
    v.y = (unsigned int)h[g * 8 + 2] | ((unsigned int)h[g * 8 + 3] << 16);
    v.z = (unsigned int)h[g * 8 + 4] | ((unsigned int)h[g * 8 + 5] << 16);
    v.w = (unsigned int)h[g * 8 + 6] | ((unsigned int)h[g * 8 + 7] << 16);
    xbr[g] = v;
  }
#pragma unroll
  for (int k = 0; k < 16; ++k) tile[(part * 16 + k) * 72 + rloc] = h[k];
  msum += __shfl_xor(msum, 1, 64);
  msum += __shfl_xor(msum, 2, 64);
  if (part == 0) m[r] = msum;
  __syncthreads();
  int d = t >> 2, seg = t & 3;
  int b = r0 >> 13;
  int tcol = (r0 & (TT - 1)) + seg * 16;
  uint4 v0 = *(uint4*)(tile + d * 72 + seg * 16);
  uint4 v1 = *(uint4*)(tile + d * 72 + seg * 16 + 8);
  uint4* dst = (uint4*)(xt + ((size_t)b * DD + d) * TT + tcol);
  dst[0] = v0;
  dst[1] = v1;
}

// ---------- kb: mm_j = m_j + ln( sum_k exp(x_j.x_k - m_j) ) (R3 verbatim) ----------
__global__ __launch_bounds__(512, 2) void kb_l(const unsigned short* __restrict__ xq,
                                               const float* __restrict__ m,
                                               float* __restrict__ mm) {
  __shared__ __align__(16) unsigned short kslab[8][2][2048];
  __shared__ float lpart[8][32];
  int w = threadIdx.x >> 6, lane = threadIdx.x & 63;
  int c = lane & 15, q = lane >> 4;
  int lid = blockIdx.x;
  int b = (lid >> 2) & 1;
  int tile = (lid & 3) | ((lid >> 3) << 2);  // 0..255
  int j0g = b * TT + tile * 32;
  bf16x8 a0[2], a1[2];
  f32x4 mv[2];
#pragma unroll
  for (int u = 0; u < 2; ++u) {
    const unsigned short* pr = xq + (size_t)(j0g + u * 16 + c) * DD + q * 8;
    a0[u] = *(const bf16x8*)pr;
    a1[u] = *(const bf16x8*)(pr + 32);
    mv[u] = *(const f32x4*)(m + j0g + u * 16 + 4 * q);
  }
  const unsigned short* xqb = xq + (size_t)(b * TT) * DD;
  int k0 = w * 1024;
  int srow = lane >> 3;
  int sch = (lane & 7) ^ srow;
  unsigned short* sb = &kslab[w][0][0];
  auto stage = [&](int buf, int kbase) {
#pragma unroll
    for (int t = 0; t < 4; ++t)
      gld_lds16(xqb + (size_t)(kbase + t * 8 + srow) * DD + sch * 8,
                sb + buf * 2048 + t * 512);
  };
  stage(0, k0);
  float ls[2][4] = {{0.f, 0.f, 0.f, 0.f}, {0.f, 0.f, 0.f, 0.f}};
  int o1 = (q ^ (c & 7)) * 8, o2 = ((q | 4) ^ (c & 7)) * 8;
  for (int it = 0; it < 32; ++it) {
    if (it < 31) {
      stage((it & 1) ^ 1, k0 + (it + 1) * 32);
      asm volatile("s_waitcnt vmcnt(4)" ::: "memory");
    } else {
      asm volatile("s_waitcnt vmcnt(0)" ::: "memory");
    }
    __builtin_amdgcn_sched_barrier(0);
    const unsigned short* kp = sb + (it & 1) * 2048;
    bf16x8 b00 = *(const bf16x8*)(kp + c * 64 + o1);
    bf16x8 b01 = *(const bf16x8*)(kp + c * 64 + o2);
    bf16x8 b10 = *(const bf16x8*)(kp + (c + 16) * 64 + o1);
    bf16x8 b11 = *(const bf16x8*)(kp + (c + 16) * 64 + o2);
    __builtin_amdgcn_s_setprio(1);
#pragma unroll
    for (int u = 0; u < 2; ++u) {
      f32x4 z = {0.f, 0.f, 0.f, 0.f};
      f32x4 acc0 = MFMA32(a0[u], b00, z, 0, 0, 0);
      acc0 = MFMA32(a1[u], b01, acc0, 0, 0, 0);
      f32x4 acc1 = MFMA32(a0[u], b10, z, 0, 0, 0);
      acc1 = MFMA32(a1[u], b11, acc1, 0, 0, 0);
#pragma unroll
      for (int e = 0; e < 4; ++e)
        ls[u][e] += __expf(acc0[e] - mv[u][e]) + __expf(acc1[e] - mv[u][e]);
    }
    __builtin_amdgcn_s_setprio(0);
  }
#pragma unroll
  for (int u = 0; u < 2; ++u)
#pragma unroll
    for (int e = 0; e < 4; ++e) {
      float v = ls[u][e];
      v += __shfl_xor(v, 1, 64);
      v += __shfl_xor(v, 2, 64);
      v += __shfl_xor(v, 4, 64);
      v += __shfl_xor(v, 8, 64);
      if (c == 0) lpart[w][u * 16 + 4 * q + e] = v;
    }
  __syncthreads();
  int t = threadIdx.x;
  if (t < 32) {
    float s = 0.f;
#pragma unroll
    for (int w2 = 0; w2 < 8; ++w2) s += lpart[w2][t];
    mm[j0g + t] = m[j0g + t] + __logf(s);
  }
}

// ---------- kc: out[b][d][i] = sum_j exp(x_j.x_i - mm_j) * x_j[d] ----------
// R3's verified pipeline with i-TILE 64 (u-loop 0..3): same per-iter staging
// (2 A-DMA + 2 V-DMA + 1 mm load per 16-j chunk) now feeds 2x the compute ->
// per-CU VMEM instructions halve (the measured ~55cy/VMEM invariant is the
// binding resource). Grid 256 = 1 block/CU, 2 waves/SIMD (R0-proven rate).
// Epilogue: two 32-i rounds of the proven 73.7KB O-reduce overlay.
__global__ __launch_bounds__(512, 1) void kc_out(const unsigned short* __restrict__ xq,
                                                 const unsigned short* __restrict__ xt,
                                                 const float* __restrict__ mm,
                                                 float* __restrict__ out) {
  __shared__ __align__(16) unsigned short smem[36864];  // A 8x4KB | V 8x4KB = 64KB | 73.7KB epilogue overlay
  int w = threadIdx.x >> 6, lane = threadIdx.x & 63;
  int c = lane & 15, q = lane >> 4;
  int lid = blockIdx.x;  // 0..255
  int b = (lid >> 2) & 1;
  int tile = (lid & 3) | ((lid >> 3) << 2);  // 0..127
  int i0 = tile * 64;
  bf16x8 bq0[4], bq1[4];
#pragma unroll
  for (int u = 0; u < 4; ++u) {
    const unsigned short* pr = xq + (size_t)(b * TT + i0 + u * 16 + c) * DD + q * 8;
    bq0[u] = *(const bf16x8*)pr;
    bq1[u] = *(const bf16x8*)(pr + 32);
  }
  f32x4 o[4][4];
#pragma unroll
  for (int u = 0; u < 4; ++u)
#pragma unroll
    for (int nt = 0; nt < 4; ++nt) o[u][nt] = (f32x4){0.f, 0.f, 0.f, 0.f};

  const unsigned short* xqb = xq + (size_t)(b * TT) * DD;
  const unsigned short* xtb = xt + (size_t)b * DD * TT;
  const float* mmb = mm + b * TT;
  int jq0 = w * 1024;
  unsigned short* asb = smem + w * 2048;           // 2 bufs x 1024 shorts (16 rows x 128B)
  unsigned short* vsb = smem + 16384 + w * 2048;   // 2 bufs x 1024 shorts (64 rows x 32B)
  int srow = lane >> 3;
  int sch = (lane & 7) ^ srow;        // A source-granule swizzle (verified R3)
  int vrow = lane >> 1;               // V: 32 d-rows per DMA
  int vg = (lane & 1) ^ (vrow & 1);   // V source-granule swizzle (verified R3)
  auto stage = [&](int buf, int j) {
#pragma unroll
    for (int t = 0; t < 2; ++t)
      gld_lds16(xqb + (size_t)(j + t * 8 + srow) * DD + sch * 8,
                asb + buf * 1024 + t * 512);
#pragma unroll
    for (int t = 0; t < 2; ++t)
      gld_lds16(xtb + (size_t)(t * 32 + vrow) * TT + j + vg * 8,
                vsb + buf * 1024 + t * 512);
  };
  stage(0, jq0);
  f32x4 cmm = *(const f32x4*)(mmb + jq0 + 4 * q);

  int o1 = (q ^ (c & 7)) * 8, o2 = ((q | 4) ^ (c & 7)) * 8;
  int vglo = (((q >> 1) ^ (c & 1)) * 8) + (q & 1) * 4;  // shorts offset in 16-short V row (verified R3)

  for (int it = 0; it < 64; ++it) {
    int jc = jq0 + it * 16;
    f32x4 nmm = cmm;
    if (it < 63) {
      nmm = *(const f32x4*)(mmb + jc + 16 + 4 * q);
      stage((it & 1) ^ 1, jc + 16);
      asm volatile("s_waitcnt vmcnt(4)" ::: "memory");  // leave next-iter's 4 DMAs in flight
    } else {
      asm volatile("s_waitcnt vmcnt(0)" ::: "memory");
    }
    __builtin_amdgcn_sched_barrier(0);
    const unsigned short* ap = asb + (it & 1) * 1024;
    const unsigned short* vp = vsb + (it & 1) * 1024;
    bf16x8 a00 = *(const bf16x8*)(ap + c * 64 + o1);
    bf16x8 a01 = *(const bf16x8*)(ap + c * 64 + o2);
    bf16x4 bv[4];
#pragma unroll
    for (int nt = 0; nt < 4; ++nt)
      bv[nt] = *(const bf16x4*)(vp + (nt * 16 + c) * 16 + vglo);
    __builtin_amdgcn_s_setprio(1);
#pragma unroll
    for (int u = 0; u < 4; ++u) {
      f32x4 z = {0.f, 0.f, 0.f, 0.f};
      f32x4 s0 = MFMA32(a00, bq0[u], z, 0, 0, 0);
      s0 = MFMA32(a01, bq1[u], s0, 0, 0, 0);
      float w00 = __expf(s0[0] - cmm[0]);
      float w01 = __expf(s0[1] - cmm[1]);
      float w02 = __expf(s0[2] - cmm[2]);
      float w03 = __expf(s0[3] - cmm[3]);
      union { unsigned int uu[2]; bf16x4 v; } plo;
      plo.uu[0] = pk2bf(w00, w01);
      plo.uu[1] = pk2bf(w02, w03);
      o[u][0] = pv_mfma16(plo.v, bv[0], o[u][0]);
      o[u][1] = pv_mfma16(plo.v, bv[1], o[u][1]);
      o[u][2] = pv_mfma16(plo.v, bv[2], o[u][2]);
      o[u][3] = pv_mfma16(plo.v, bv[3], o[u][3]);
    }
    __builtin_amdgcn_s_setprio(0);
    cmm = nmm;
  }
  // cross-wave O reduce, two 32-i rounds of the proven Olds[w][64 d][36] overlay
#pragma unroll
  for (int r = 0; r < 2; ++r) {
    __syncthreads();
    float* ow = (float*)smem + w * 2304;
#pragma unroll
    for (int u2 = 0; u2 < 2; ++u2)
#pragma unroll
      for (int nt = 0; nt < 4; ++nt)
        *(f32x4*)(ow + (nt * 16 + c) * 36 + u2 * 16 + 4 * q) = o[r * 2 + u2][nt];
    __syncthreads();
    int t = threadIdx.x, d = t & 63, g = t >> 6;  // g = 0..7 -> 4 i's each
    const float* sbase = (const float*)smem;
    f32x4 sA = {0.f, 0.f, 0.f, 0.f};
#pragma unroll
    for (int w2 = 0; w2 < 8; ++w2)
      sA += *(const f32x4*)(sbase + w2 * 2304 + d * 36 + g * 4);
    *(f32x4*)(out + ((size_t)(b * DD + d)) * TT + i0 + r * 32 + g * 4) = sA;
  }
}

extern "C" void kernel_launch(void* const* d_in, const int* in_sizes, int n_in,
                              void* d_out, int out_size, void* d_ws, size_t ws_size,
                              hipStream_t stream) {
  const float* x = (const float*)d_in[0];
  float* out = (float*)d_out;
  unsigned short* xb = (unsigned short*)d_ws;
  unsigned short* xt = xb + (size_t)NROWS * DD;
  float* m = (float*)(xt + (size_t)NROWS * DD);
  float* mmv = m + NROWS;

  ka_init<<<NROWS / 64, 256, 0, stream>>>(x, xb, xt, m);
  kb_l<<<512, 512, 0, stream>>>(xb, m, mmv);
  kc_out<<<256, 512, 0, stream>>>(xb, xt, mmv, out);
}

// Round 11
// 147.048 us; speedup vs baseline: 1.5551x; 1.0089x over previous
//
#include <hip/hip_runtime.h>
#include <hip/hip_bf16.h>

#define TT 8192
#define DD 64
#define BB 2
#define NROWS (BB * TT)  // 16384

typedef __attribute__((ext_vector_type(8))) short bf16x8;
typedef __attribute__((ext_vector_type(4))) short bf16x4;
typedef __attribute__((ext_vector_type(4))) float f32x4;

#define MFMA32 __builtin_amdgcn_mfma_f32_16x16x32_bf16

// PV matmul: legacy K=16 shape whose A-operand layout (row=lane&15,
// k=(lane>>4)*4+e) matches the S-MFMA D-layout directly -> no lane shuffle.
// (verified passing rounds 1-10)
static __device__ inline f32x4 pv_mfma16(bf16x4 a, bf16x4 b, f32x4 c) {
#if __has_builtin(__builtin_amdgcn_mfma_f32_16x16x16bf16_1k)
  return __builtin_amdgcn_mfma_f32_16x16x16bf16_1k(a, b, c, 0, 0, 0);
#else
  asm volatile("v_mfma_f32_16x16x16_bf16 %0, %1, %2, %0" : "+v"(c) : "v"(a), "v"(b));
  return c;
#endif
}

typedef __attribute__((address_space(1))) const unsigned int gu32;
typedef __attribute__((address_space(3))) unsigned int lu32;

// async global->LDS, 16B per lane; LDS dest = wave-uniform base + lane*16
__device__ inline void gld_lds16(const unsigned short* g, unsigned short* l) {
  __builtin_amdgcn_global_load_lds((gu32*)g, (lu32*)l, 16, 0, 0);
}

// ws layout: xb bf16[16384*64] (2MB) | xt bf16[2*64*8192] (2MB) | m fp32[16384]
//          | mm fp32[16384] | Z fp32[16384]

__device__ inline unsigned short f2bf(float f) {
  unsigned int u = __float_as_uint(f);
  u += 0x7FFF + ((u >> 16) & 1);  // RNE
  return (unsigned short)(u >> 16);
}
__device__ inline float bf2f(unsigned short h) {
  return __uint_as_float(((unsigned int)h) << 16);
}
__device__ inline unsigned int pk2bf(float lo, float hi) {
  __hip_bfloat162 h = __float22bfloat162_rn(float2{lo, hi});
  union { __hip_bfloat162 h; unsigned int u; } cv;
  cv.h = h;
  return cv.u;
}

// ---------- ka: bf16 convert + m + xb + LDS-transposed xt + Z zero ----------
__global__ __launch_bounds__(256) void ka_init(const float* __restrict__ x,
                                               unsigned short* __restrict__ xb,
                                               unsigned short* __restrict__ xt,
                                               float* __restrict__ m,
                                               float* __restrict__ Z) {
  __shared__ __align__(16) unsigned short tile[64 * 72];
  int t = threadIdx.x;
  int r0 = blockIdx.x * 64;
  if (t < 64) Z[r0 + t] = 0.f;  // pre-zero Z for kb_tri atomics
  int rloc = t >> 2, part = t & 3;
  int r = r0 + rloc;
  const float4* px = (const float4*)(x + (size_t)r * DD + part * 16);
  unsigned short h[16];
  float msum = 0.f;
#pragma unroll
  for (int g = 0; g < 4; ++g) {
    float4 v = px[g];
    unsigned short h0 = f2bf(v.x), h1 = f2bf(v.y), h2 = f2bf(v.z), h3 = f2bf(v.w);
    h[g * 4 + 0] = h0; h[g * 4 + 1] = h1; h[g * 4 + 2] = h2; h[g * 4 + 3] = h3;
    float f0 = bf2f(h0), f1 = bf2f(h1), f2 = bf2f(h2), f3 = bf2f(h3);
    msum += f0 * f0 + f1 * f1 + f2 * f2 + f3 * f3;
  }
  uint4* xbr = (uint4*)(xb + (size_t)r * DD + part * 16);
#pragma unroll
  for (int g = 0; g < 2; ++g) {
    uint4 v;
    v.x = (unsigned int)h[g * 8 + 0] | ((unsigned int)h[g * 8 + 1] << 16);
    v.y = (unsigned int)h[g * 8 + 2] | ((unsigned int)h[g * 8 + 3] << 16);
    v.z = (unsigned int)h[g * 8 + 4] | ((unsigned int)h[g * 8 + 5] << 16);
    v.w = (unsigned int)h[g * 8 + 6] | ((unsigned int)h[g * 8 + 7] << 16);
    xbr[g] = v;
  }
#pragma unroll
  for (int k = 0; k < 16; ++k) tile[(part * 16 + k) * 72 + rloc] = h[k];
  msum += __shfl_xor(msum, 1, 64);
  msum += __shfl_xor(msum, 2, 64);
  if (part == 0) m[r] = msum;
  __syncthreads();
  int d = t >> 2, seg = t & 3;
  int b = r0 >> 13;
  int tcol = (r0 & (TT - 1)) + seg * 16;
  uint4 v0 = *(uint4*)(tile + d * 72 + seg * 16);
  uint4 v1 = *(uint4*)(tile + d * 72 + seg * 16 + 8);
  uint4* dst = (uint4*)(xt + ((size_t)b * DD + d) * TT + tcol);
  dst[0] = v0;
  dst[1] = v1;
}

// ---------- kb_tri: Z_j += sum_k exp(x_j.x_k - m_j), triangular ----------
// Gram symmetry: E[j,k]=E[k,j]. Each block computes ONE 128x128 group-pair
// tile (ga<=gb) and credits both groups: row-sums -> Z[gA rows]; col-sums
// (q-axis shuffle of the verified C layout) -> Z[gB rows]; diagonal tiles
// row-sums only. Halves kb's MFMA/exp/staging. Fragment math, slab geometry,
// XOR staging, row-reduce all verbatim from the verified kb.
__global__ __launch_bounds__(512, 3) void kb_tri(const unsigned short* __restrict__ xq,
                                                 const float* __restrict__ m,
                                                 float* __restrict__ Z) {
  __shared__ __align__(16) unsigned short slab[128 * 64];  // 16KB: gB's 128 rows
  __shared__ float colp[8][128];                           // 4KB col partials
  int w = threadIdx.x >> 6, lane = threadIdx.x & 63;
  int c = lane & 15, q = lane >> 4;
  int x = blockIdx.x;
  int b = (x >= 2080) ? 1 : 0;   // 2080 = 64*65/2 pairs per batch
  int p = x - b * 2080;
  // decode (ga <= gb) over 64 groups: offset(ga) = ga*64 - ga*(ga-1)/2
  int ga = (int)((129.0f - sqrtf(16641.0f - 8.0f * (float)p)) * 0.5f);
  while (ga > 0 && ga * 64 - ga * (ga - 1) / 2 > p) --ga;
  while ((ga + 1) * 64 - (ga + 1) * ga / 2 <= p) ++ga;
  int gb = ga + (p - (ga * 64 - ga * (ga - 1) / 2));
  int jA = b * TT + ga * 128;
  int jB = b * TT + gb * 128;
  bool diag = (ga == gb);
  // stage gB's 128 rows (16 DMAs, 2/wave), same 8-row-granule geometry as kb
  int srow = lane >> 3;
  int sch = (lane & 7) ^ srow;
#pragma unroll
  for (int t = 0; t < 2; ++t)
    gld_lds16(xq + (size_t)(jB + (w * 2 + t) * 8 + srow) * DD + sch * 8,
              slab + (w * 2 + t) * 512);
  // A-frags: this wave's 16 rows of gA (verified pattern, u -> w)
  const unsigned short* pr = xq + (size_t)(jA + w * 16 + c) * DD + q * 8;
  bf16x8 a0 = *(const bf16x8*)pr;
  bf16x8 a1 = *(const bf16x8*)(pr + 32);
  f32x4 mv = *(const f32x4*)(m + jA + w * 16 + 4 * q);
  int o1 = (q ^ (c & 7)) * 8, o2 = ((q | 4) ^ (c & 7)) * 8;
  float rs[4] = {0.f, 0.f, 0.f, 0.f};
  asm volatile("s_waitcnt vmcnt(0)" ::: "memory");
  __syncthreads();
#pragma unroll
  for (int kc2 = 0; kc2 < 4; ++kc2) {
    const unsigned short* kp = slab + kc2 * 2048;
    bf16x8 b00 = *(const bf16x8*)(kp + c * 64 + o1);
    bf16x8 b01 = *(const bf16x8*)(kp + c * 64 + o2);
    bf16x8 b10 = *(const bf16x8*)(kp + (c + 16) * 64 + o1);
    bf16x8 b11 = *(const bf16x8*)(kp + (c + 16) * 64 + o2);
    __builtin_amdgcn_s_setprio(1);
    f32x4 z = {0.f, 0.f, 0.f, 0.f};
    f32x4 acc0 = MFMA32(a0, b00, z, 0, 0, 0);
    acc0 = MFMA32(a1, b01, acc0, 0, 0, 0);
    f32x4 acc1 = MFMA32(a0, b10, z, 0, 0, 0);
    acc1 = MFMA32(a1, b11, acc1, 0, 0, 0);
    __builtin_amdgcn_s_setprio(0);
    float e0[4], e1[4];
#pragma unroll
    for (int e = 0; e < 4; ++e) {
      e0[e] = __expf(acc0[e] - mv[e]);   // E[j = jA+w*16+4q+e, k = jB+kc2*32+c]
      e1[e] = __expf(acc1[e] - mv[e]);   // E[j, k = jB+kc2*32+16+c]
      rs[e] += e0[e] + e1[e];
    }
    if (!diag) {
      // col sums: sum over this wave's 16 j = sum over e (in-lane) + q (xor 16,32)
      float clo = e0[0] + e0[1] + e0[2] + e0[3];
      float chi = e1[0] + e1[1] + e1[2] + e1[3];
      clo += __shfl_xor(clo, 16, 64); clo += __shfl_xor(clo, 32, 64);
      chi += __shfl_xor(chi, 16, 64); chi += __shfl_xor(chi, 32, 64);
      if (q == 0) {
        colp[w][kc2 * 32 + c] = clo;
        colp[w][kc2 * 32 + 16 + c] = chi;
      }
    }
  }
  // row sums -> Z[gA rows] (verified c-axis reduce)
#pragma unroll
  for (int e = 0; e < 4; ++e) {
    float v = rs[e];
    v += __shfl_xor(v, 1, 64); v += __shfl_xor(v, 2, 64);
    v += __shfl_xor(v, 4, 64); v += __shfl_xor(v, 8, 64);
    if (c == 0) atomicAdd(Z + jA + w * 16 + 4 * q + e, v);
  }
  if (!diag) {
    __syncthreads();
    int t = threadIdx.x;
    if (t < 128) {
      float s = 0.f;
#pragma unroll
      for (int w2 = 0; w2 < 8; ++w2) s += colp[w2][t];
      atomicAdd(Z + jB + t, s);
    }
  }
}

// ---------- kz: mm = m + log(Z) ----------
__global__ __launch_bounds__(512) void kz_fin(const float* __restrict__ m,
                                              const float* __restrict__ Z,
                                              float* __restrict__ mm) {
  int r = blockIdx.x * 512 + threadIdx.x;
  mm[r] = m[r] + __logf(Z[r]);
}

// ---------- kc: out[b][d][i] = sum_j exp(x_j.x_i - mm_j) * x_j[d] ----------
// R10 winner, verbatim: i-tile 64, R3 pipeline, 5 VMEM per 16-j chunk.
__global__ __launch_bounds__(512, 1) void kc_out(const unsigned short* __restrict__ xq,
                                                 const unsigned short* __restrict__ xt,
                                                 const float* __restrict__ mm,
                                                 float* __restrict__ out) {
  __shared__ __align__(16) unsigned short smem[36864];  // A 8x4KB | V 8x4KB = 64KB | 73.7KB epilogue overlay
  int w = threadIdx.x >> 6, lane = threadIdx.x & 63;
  int c = lane & 15, q = lane >> 4;
  int lid = blockIdx.x;  // 0..255
  int b = (lid >> 2) & 1;
  int tile = (lid & 3) | ((lid >> 3) << 2);  // 0..127
  int i0 = tile * 64;
  bf16x8 bq0[4], bq1[4];
#pragma unroll
  for (int u = 0; u < 4; ++u) {
    const unsigned short* pr = xq + (size_t)(b * TT + i0 + u * 16 + c) * DD + q * 8;
    bq0[u] = *(const bf16x8*)pr;
    bq1[u] = *(const bf16x8*)(pr + 32);
  }
  f32x4 o[4][4];
#pragma unroll
  for (int u = 0; u < 4; ++u)
#pragma unroll
    for (int nt = 0; nt < 4; ++nt) o[u][nt] = (f32x4){0.f, 0.f, 0.f, 0.f};

  const unsigned short* xqb = xq + (size_t)(b * TT) * DD;
  const unsigned short* xtb = xt + (size_t)b * DD * TT;
  const float* mmb = mm + b * TT;
  int jq0 = w * 1024;
  unsigned short* asb = smem + w * 2048;           // 2 bufs x 1024 shorts (16 rows x 128B)
  unsigned short* vsb = smem + 16384 + w * 2048;   // 2 bufs x 1024 shorts (64 rows x 32B)
  int srow = lane >> 3;
  int sch = (lane & 7) ^ srow;        // A source-granule swizzle (verified R3)
  int vrow = lane >> 1;               // V: 32 d-rows per DMA
  int vg = (lane & 1) ^ (vrow & 1);   // V source-granule swizzle (verified R3)
  auto stage = [&](int buf, int j) {
#pragma unroll
    for (int t = 0; t < 2; ++t)
      gld_lds16(xqb + (size_t)(j + t * 8 + srow) * DD + sch * 8,
                asb + buf * 1024 + t * 512);
#pragma unroll
    for (int t = 0; t < 2; ++t)
      gld_lds16(xtb + (size_t)(t * 32 + vrow) * TT + j + vg * 8,
                vsb + buf * 1024 + t * 512);
  };
  stage(0, jq0);
  f32x4 cmm = *(const f32x4*)(mmb + jq0 + 4 * q);

  int o1 = (q ^ (c & 7)) * 8, o2 = ((q | 4) ^ (c & 7)) * 8;
  int vglo = (((q >> 1) ^ (c & 1)) * 8) + (q & 1) * 4;  // shorts offset in 16-short V row (verified R3)

  for (int it = 0; it < 64; ++it) {
    int jc = jq0 + it * 16;
    f32x4 nmm = cmm;
    if (it < 63) {
      nmm = *(const f32x4*)(mmb + jc + 16 + 4 * q);
      stage((it & 1) ^ 1, jc + 16);
      asm volatile("s_waitcnt vmcnt(4)" ::: "memory");  // leave next-iter's 4 DMAs in flight
    } else {
      asm volatile("s_waitcnt vmcnt(0)" ::: "memory");
    }
    __builtin_amdgcn_sched_barrier(0);
    const unsigned short* ap = asb + (it & 1) * 1024;
    const unsigned short* vp = vsb + (it & 1) * 1024;
    bf16x8 a00 = *(const bf16x8*)(ap + c * 64 + o1);
    bf16x8 a01 = *(const bf16x8*)(ap + c * 64 + o2);
    bf16x4 bv[4];
#pragma unroll
    for (int nt = 0; nt < 4; ++nt)
      bv[nt] = *(const bf16x4*)(vp + (nt * 16 + c) * 16 + vglo);
    __builtin_amdgcn_s_setprio(1);
#pragma unroll
    for (int u = 0; u < 4; ++u) {
      f32x4 z = {0.f, 0.f, 0.f, 0.f};
      f32x4 s0 = MFMA32(a00, bq0[u], z, 0, 0, 0);
      s0 = MFMA32(a01, bq1[u], s0, 0, 0, 0);
      float w00 = __expf(s0[0] - cmm[0]);
      float w01 = __expf(s0[1] - cmm[1]);
      float w02 = __expf(s0[2] - cmm[2]);
      float w03 = __expf(s0[3] - cmm[3]);
      union { unsigned int uu[2]; bf16x4 v; } plo;
      plo.uu[0] = pk2bf(w00, w01);
      plo.uu[1] = pk2bf(w02, w03);
      o[u][0] = pv_mfma16(plo.v, bv[0], o[u][0]);
      o[u][1] = pv_mfma16(plo.v, bv[1], o[u][1]);
      o[u][2] = pv_mfma16(plo.v, bv[2], o[u][2]);
      o[u][3] = pv_mfma16(plo.v, bv[3], o[u][3]);
    }
    __builtin_amdgcn_s_setprio(0);
    cmm = nmm;
  }
  // cross-wave O reduce, two 32-i rounds of the proven Olds[w][64 d][36] overlay
#pragma unroll
  for (int r = 0; r < 2; ++r) {
    __syncthreads();
    float* ow = (float*)smem + w * 2304;
#pragma unroll
    for (int u2 = 0; u2 < 2; ++u2)
#pragma unroll
      for (int nt = 0; nt < 4; ++nt)
        *(f32x4*)(ow + (nt * 16 + c) * 36 + u2 * 16 + 4 * q) = o[r * 2 + u2][nt];
    __syncthreads();
    int t = threadIdx.x, d = t & 63, g = t >> 6;  // g = 0..7 -> 4 i's each
    const float* sbase = (const float*)smem;
    f32x4 sA = {0.f, 0.f, 0.f, 0.f};
#pragma unroll
    for (int w2 = 0; w2 < 8; ++w2)
      sA += *(const f32x4*)(sbase + w2 * 2304 + d * 36 + g * 4);
    *(f32x4*)(out + ((size_t)(b * DD + d)) * TT + i0 + r * 32 + g * 4) = sA;
  }
}

extern "C" void kernel_launch(void* const* d_in, const int* in_sizes, int n_in,
                              void* d_out, int out_size, void* d_ws, size_t ws_size,
                              hipStream_t stream) {
  const float* x = (const float*)d_in[0];
  float* out = (float*)d_out;
  unsigned short* xb = (unsigned short*)d_ws;
  unsigned short* xt = xb + (size_t)NROWS * DD;
  float* m = (float*)(xt + (size_t)NROWS * DD);
  float* mmv = m + NROWS;
  float* Z = mmv + NROWS;

  ka_init<<<NROWS / 64, 256, 0, stream>>>(x, xb, xt, m, Z);
  kb_tri<<<2 * 2080, 512, 0, stream>>>(xb, m, Z);
  kz_fin<<<NROWS / 512, 512, 0, stream>>>(m, Z, mmv);
  kc_out<<<256, 512, 0, stream>>>(xb, xt, mmv, out);
}